// Round 1
// baseline (379.308 us; speedup 1.0000x reference)
//
#include <hip/hip_runtime.h>
#include <math.h>

#define NN 8192
#define EE 131072
#define CC 64
#define GG 32

__device__ __forceinline__ float silu_f(float x) { return x / (1.0f + expf(-x)); }

// ---------------- h0 = node_attrs @ W_embed ; elem = argmax(node_attrs) -------------
__global__ __launch_bounds__(64) void k_h0(const float* __restrict__ na,
                                           const float* __restrict__ Wemb,
                                           float* __restrict__ h0,
                                           int* __restrict__ elem) {
    int n = blockIdx.x;
    int d = threadIdx.x;
    float acc = 0.0f;
    float best = -1.0f; int bi = 0;
    #pragma unroll
    for (int k = 0; k < 10; k++) {
        float a = na[n * 10 + k];
        acc += a * Wemb[k * 64 + d];
        if (a > best) { best = a; bi = k; }
    }
    h0[n * 64 + d] = acc;
    if (d == 0) elem[n] = bi;
}

// ---------------- edge message + scatter (only k=0..3 are live downstream) ----------
// A[n,k,c], k=0..3 :  A[n,0,c] = (1/16) sum_e h[snd,c]*wrf0[c]
//                     A[n,k,c] = (1/16) sum_e sqrt3*u_{k-1}*h[snd,c]*wrf1[c]
__global__ __launch_bounds__(256) void edge_scatter(
    const float* __restrict__ feats,  // (N,C) node features (h0 or out0)
    const float* __restrict__ pos,    // (N,3)
    const float* __restrict__ shifts, // (E,3)
    const int*   __restrict__ eidx,   // (2,E)
    const float* __restrict__ Wra,    // (8,64)
    const float* __restrict__ Wrb,    // (64,256) -> cols 0..127 used
    float* __restrict__ A)            // (N,4,C)
{
    __shared__ float sWa[8 * 64];
    __shared__ float sWb[64 * 128];
    int tid = threadIdx.x;
    for (int i = tid; i < 8 * 64; i += 256) sWa[i] = Wra[i];
    for (int i = tid; i < 64 * 128; i += 256) sWb[i] = Wrb[(i >> 7) * 256 + (i & 127)];
    __syncthreads();

    int lane  = tid & 63;
    int gwave = (blockIdx.x * 256 + tid) >> 6;
    int nwave = (gridDim.x * 256) >> 6;
    const float PI = 3.14159265358979f;

    for (int e = gwave; e < EE; e += nwave) {
        int snd = eidx[e];
        int rcv = eidx[EE + e];
        float vx = pos[rcv * 3 + 0] - pos[snd * 3 + 0] + shifts[e * 3 + 0];
        float vy = pos[rcv * 3 + 1] - pos[snd * 3 + 1] + shifts[e * 3 + 1];
        float vz = pos[rcv * 3 + 2] - pos[snd * 3 + 2] + shifts[e * 3 + 2];
        float r2 = vx * vx + vy * vy + vz * vz + 1e-12f;
        float r = sqrtf(r2);
        float x = r * 0.2f;                 // r / RMAX
        if (!(x < 1.0f)) continue;          // envelope==0 -> message exactly 0
        float rinv = 1.0f / r;
        float ux = vx * rinv, uy = vy * rinv, uz = vz * rinv;
        float x2 = x * x, x4 = x2 * x2, x5 = x4 * x;
        float env = 1.0f - 21.0f * x5 + 35.0f * x5 * x - 15.0f * x5 * x2;
        float pref = 0.632455532033676f * rinv * env;   // sqrt(2/5)/r * env

        // hidden[lane] = silu( sum_b rb[b] * Wra[b][lane] )
        float hacc = 0.0f;
        #pragma unroll
        for (int b = 0; b < 8; b++) {
            float rb = pref * sinf((float)(b + 1) * (PI * 0.2f) * r);
            hacc += rb * sWa[b * 64 + lane];
        }
        float hid = silu_f(hacc);

        // wrf0/wrf1[lane] = sum_j hidden[j] * Wrb[j][l*64+lane], l=0,1
        float w0 = 0.0f, w1 = 0.0f;
        for (int j = 0; j < 64; j++) {
            float hj = __shfl(hid, j);
            w0 += hj * sWb[j * 128 + lane];
            w1 += hj * sWb[j * 128 + 64 + lane];
        }

        float base = feats[snd * CC + lane] * (1.0f / 16.0f);  // /AVG
        float a0 = base * w0;
        float g  = base * w1 * 1.732050807568877f;             // sqrt(3)
        float* Ar = A + (size_t)rcv * (4 * CC);
        atomicAdd(Ar + lane,       a0);
        atomicAdd(Ar + 64 + lane,  g * ux);
        atomicAdd(Ar + 128 + lane, g * uy);
        atomicAdd(Ar + 192 + lane, g * uz);
    }
}

// ---------------- node update 1 -----------------------------------------------------
__global__ __launch_bounds__(64) void node1(
    const float* __restrict__ h0, const int* __restrict__ elem,
    const float* __restrict__ A,
    const float* __restrict__ Wmix1,  // (4,64,64): use l=0,1
    const float* __restrict__ Wsc1,   // (10,64,64)
    const float* __restrict__ Wp1s,   // (3,10,64)
    const float* __restrict__ Wp1v,   // (3,10,64)
    const float* __restrict__ Wp10,   // (64,64)
    const float* __restrict__ Wp11,   // (64,64)
    const float* __restrict__ wrd1,   // (64,)
    float* __restrict__ out0, float* __restrict__ out1, float* __restrict__ d1)
{
    int n = blockIdx.x;
    int d = threadIdx.x;
    __shared__ float sA[4 * 64];
    __shared__ float sh0[64];
    __shared__ float sm0[64];
    __shared__ float st[3 * 64];

    #pragma unroll
    for (int k = 0; k < 4; k++) sA[k * 64 + d] = A[(size_t)n * 256 + k * 64 + d];
    sh0[d] = h0[n * 64 + d];
    __syncthreads();

    int en = elem[n];
    float h1v[4];
    #pragma unroll
    for (int k = 0; k < 4; k++) {
        const float* Wm = Wmix1 + (k ? 4096 : 0);
        float acc = 0.0f;
        for (int c = 0; c < 64; c++) acc += sA[k * 64 + c] * Wm[c * 64 + d];
        h1v[k] = acc;
    }
    const float* Ws = Wsc1 + en * 4096;
    float sc = 0.0f;
    for (int c = 0; c < 64; c++) sc += sh0[c] * Ws[c * 64 + d];

    float s = h1v[0];
    float ws0 = Wp1s[en * 64 + d], ws1 = Wp1s[640 + en * 64 + d], ws2 = Wp1s[1280 + en * 64 + d];
    float wv0 = Wp1v[en * 64 + d], wv1 = Wp1v[640 + en * 64 + d], wv2 = Wp1v[1280 + en * 64 + d];
    float m0 = ws0 * s + ws1 * s * s + ws2 * s * s * s;
    float gv = wv0 + wv1 * s + wv2 * s * s;
    sm0[d] = m0;
    st[0 * 64 + d] = h1v[1] * gv;
    st[1 * 64 + d] = h1v[2] * gv;
    st[2 * 64 + d] = h1v[3] * gv;
    __syncthreads();

    float o0 = sc;
    for (int c = 0; c < 64; c++) o0 += sm0[c] * Wp10[c * 64 + d];
    out0[n * 64 + d] = o0;

    float wr = wrd1[d];
    #pragma unroll
    for (int m = 0; m < 3; m++) {
        float acc = 0.0f;
        for (int c = 0; c < 64; c++) acc += st[m * 64 + c] * Wp11[c * 64 + d];
        out1[((size_t)n * 3 + m) * 64 + d] = acc;
        float v = acc * wr;
        #pragma unroll
        for (int off = 32; off > 0; off >>= 1) v += __shfl_down(v, off);
        if (d == 0) d1[n * 3 + m] = v;
    }
}

// ---------------- node update 2 + readout -------------------------------------------
__global__ __launch_bounds__(64) void node2(
    const int* __restrict__ elem, const float* __restrict__ A,
    const float* __restrict__ out1, const float* __restrict__ d1,
    const float* __restrict__ Wmix2, const float* __restrict__ Wsc2,
    const float* __restrict__ Wpr2, const float* __restrict__ Wp2,
    const float* __restrict__ Wv, const float* __restrict__ Wg1,
    const float* __restrict__ bg1, const float* __restrict__ Wg2,
    const float* __restrict__ bg2, const float* __restrict__ wrd2,
    const int* __restrict__ batch, const float* __restrict__ chg,
    const float* __restrict__ pos,
    float* __restrict__ total, float* __restrict__ dip)
{
    int n = blockIdx.x;
    int d = threadIdx.x;
    __shared__ float sA[4 * 64];
    __shared__ float so1[3 * 64];
    __shared__ float st[3 * 64];
    __shared__ float so2[3 * 64];
    __shared__ float svh[48];
    __shared__ float sv[16];
    __shared__ float s_silu[16];
    __shared__ float s_aw[16];

    #pragma unroll
    for (int k = 0; k < 4; k++) sA[k * 64 + d] = A[(size_t)n * 256 + k * 64 + d];
    #pragma unroll
    for (int m = 0; m < 3; m++) so1[m * 64 + d] = out1[((size_t)n * 3 + m) * 64 + d];
    __syncthreads();

    int en = elem[n];
    float h2v[4];
    #pragma unroll
    for (int k = 0; k < 4; k++) {
        const float* Wm = Wmix2 + (k ? 4096 : 0);
        float acc = 0.0f;
        for (int c = 0; c < 64; c++) acc += sA[k * 64 + c] * Wm[c * 64 + d];
        h2v[k] = acc;
    }
    float s2 = h2v[0];
    float w0 = Wpr2[en * 64 + d], w1 = Wpr2[640 + en * 64 + d], w2 = Wpr2[1280 + en * 64 + d];
    float gv2 = w0 + w1 * s2 + w2 * s2 * s2;
    st[0 * 64 + d] = h2v[1] * gv2;
    st[1 * 64 + d] = h2v[2] * gv2;
    st[2 * 64 + d] = h2v[3] * gv2;
    __syncthreads();

    const float* Ws = Wsc2 + en * 4096;
    #pragma unroll
    for (int m = 0; m < 3; m++) {
        float acc = 0.0f, sc = 0.0f;
        for (int c = 0; c < 64; c++) {
            acc += st[m * 64 + c] * Wp2[c * 64 + d];
            sc  += so1[m * 64 + c] * Ws[c * 64 + d];
        }
        so2[m * 64 + d] = acc + sc;
    }
    __syncthreads();

    if (d < 48) {
        int m = d >> 4, h = d & 15;
        float acc = 0.0f;
        for (int c = 0; c < 64; c++) acc += so2[m * 64 + c] * Wv[c * 16 + h];
        svh[d] = acc;
    }
    __syncthreads();
    if (d < 16) {
        float v0 = svh[d], v1 = svh[16 + d], v2 = svh[32 + d];
        sv[d] = sqrtf(v0 * v0 + v1 * v1 + v2 * v2 + 1e-12f);
    }
    __syncthreads();
    if (d < 16) {
        float acc = bg1[d];
        for (int h = 0; h < 16; h++) acc += sv[h] * Wg1[h * 16 + d];
        s_silu[d] = silu_f(acc);
    }
    __syncthreads();
    if (d < 16) {
        float acc = bg2[d];
        for (int h = 0; h < 16; h++) acc += s_silu[h] * Wg2[h * 16 + d];
        s_aw[d] = acc * wrd2[d];
    }
    __syncthreads();
    if (d < 3) {
        float acc = 0.0f;
        for (int h = 0; h < 16; h++) acc += svh[d * 16 + h] * s_aw[h];
        float dv = d1[n * 3 + d] + acc;
        dip[n * 3 + d] = dv;
        atomicAdd(&total[batch[n] * 3 + d], dv + chg[n] * pos[n * 3 + d]);
    }
}

extern "C" void kernel_launch(void* const* d_in, const int* in_sizes, int n_in,
                              void* d_out, int out_size, void* d_ws, size_t ws_size,
                              hipStream_t stream) {
    const float* na     = (const float*)d_in[0];
    const float* pos    = (const float*)d_in[1];
    const float* shifts = (const float*)d_in[2];
    const float* chg    = (const float*)d_in[3];
    const int*   eidx   = (const int*)d_in[4];
    const int*   batch  = (const int*)d_in[5];
    const float* Wemb   = (const float*)d_in[7];
    const float* Wr1a   = (const float*)d_in[8];
    const float* Wr1b   = (const float*)d_in[9];
    const float* Wmix1  = (const float*)d_in[10];
    const float* Wsc1   = (const float*)d_in[11];
    const float* Wp1s   = (const float*)d_in[12];
    const float* Wp1v   = (const float*)d_in[13];
    const float* Wp10   = (const float*)d_in[14];
    const float* Wp11   = (const float*)d_in[15];
    const float* wrd1   = (const float*)d_in[16];
    const float* Wr2a   = (const float*)d_in[17];
    const float* Wr2b   = (const float*)d_in[18];
    const float* Wmix2  = (const float*)d_in[19];
    const float* Wsc2   = (const float*)d_in[20];
    const float* Wpr2   = (const float*)d_in[21];
    const float* Wp2    = (const float*)d_in[22];
    const float* Wv     = (const float*)d_in[23];
    const float* Wg1    = (const float*)d_in[24];
    const float* bg1    = (const float*)d_in[25];
    const float* Wg2    = (const float*)d_in[26];
    const float* bg2    = (const float*)d_in[27];
    const float* wrd2   = (const float*)d_in[28];

    float* ws   = (float*)d_ws;
    float* h0   = ws;                        // N*C
    float* A    = h0 + (size_t)NN * CC;      // N*4*C
    float* out0 = A + (size_t)NN * 4 * CC;   // N*C
    float* out1 = out0 + (size_t)NN * CC;    // N*3*C
    float* d1   = out1 + (size_t)NN * 3 * CC;// N*3
    int*   elem = (int*)(d1 + (size_t)NN * 3);

    float* total = (float*)d_out;            // G*3
    float* dip   = total + GG * 3;           // N*3

    hipMemsetAsync(A, 0, (size_t)NN * 4 * CC * sizeof(float), stream);
    hipMemsetAsync(total, 0, (size_t)GG * 3 * sizeof(float), stream);

    k_h0<<<NN, 64, 0, stream>>>(na, Wemb, h0, elem);
    edge_scatter<<<2048, 256, 0, stream>>>(h0, pos, shifts, eidx, Wr1a, Wr1b, A);
    node1<<<NN, 64, 0, stream>>>(h0, elem, A, Wmix1, Wsc1, Wp1s, Wp1v, Wp10, Wp11, wrd1,
                                 out0, out1, d1);
    hipMemsetAsync(A, 0, (size_t)NN * 4 * CC * sizeof(float), stream);
    edge_scatter<<<2048, 256, 0, stream>>>(out0, pos, shifts, eidx, Wr2a, Wr2b, A);
    node2<<<NN, 64, 0, stream>>>(elem, A, out1, d1, Wmix2, Wsc2, Wpr2, Wp2, Wv,
                                 Wg1, bg1, Wg2, bg2, wrd2, batch, chg, pos, total, dip);
}